// Round 8
// baseline (370.910 us; speedup 1.0000x reference)
//
#include <hip/hip_runtime.h>
#include <stdint.h>

#define N_NODES 50000
#define N_EDGES 500000
#define NPAD    50048   // 391 * 128
#define NSCAN   196     // ceil(50000/256)
#define EPS     1e-5f

typedef _Float16 half8_ __attribute__((ext_vector_type(8)));
typedef _Float16 half4_ __attribute__((ext_vector_type(4)));
typedef float    float4_ __attribute__((ext_vector_type(4)));

typedef uint32_t u32_g __attribute__((address_space(1)));
typedef uint32_t u32_s __attribute__((address_space(3)));

__device__ __forceinline__ void gload16(const void* g, void* lds_wave_base) {
    __builtin_amdgcn_global_load_lds((const u32_g*)g, (u32_s*)lds_wave_base, 16, 0, 0);
}

// ================= mega prep kernel =================
// block ranges: [0,490) count_rank | [490,12990) copyx | [12990,14654) wcat
//               [14654,14690) pad  | [14690,14693) bias
__global__ __launch_bounds__(256) void prep_kernel(
        const int* __restrict__ e1, const int* __restrict__ e2,
        int* __restrict__ cnt, int* __restrict__ ranks,
        const float* __restrict__ x, _Float16* __restrict__ xh,
        _Float16* __restrict__ aggb, _Float16* __restrict__ h1,
        const float* __restrict__ Wl, const float* __restrict__ W0,
        const float* __restrict__ W1, const float* __restrict__ Wout,
        _Float16* __restrict__ Wcat,
        const float* __restrict__ bl, const float* __restrict__ b0,
        const float* __restrict__ b1, const float* __restrict__ bout,
        float* __restrict__ bias) {
    const int bid = blockIdx.x;
    const int tid = threadIdx.x;
    if (bid < 490) {
        // ---- count_rank: 8 edges/thread, atomic return = rank ----
        const int set = (bid >= 245);
        const int bx  = set ? bid - 245 : bid;
        const int* dst = set ? e2 : e1;
        int* c = cnt + set * N_NODES;
        int* r = ranks + set * N_EDGES;
        int i0 = (bx * 256 + tid) * 8;
        if (i0 >= N_EDGES) return;
        int4 d0 = *(const int4*)(dst + i0);
        int4 d1 = *(const int4*)(dst + i0 + 4);
        int r0 = atomicAdd(&c[d0.x], 1);
        int r1 = atomicAdd(&c[d0.y], 1);
        int r2 = atomicAdd(&c[d0.z], 1);
        int r3 = atomicAdd(&c[d0.w], 1);
        int r4 = atomicAdd(&c[d1.x], 1);
        int r5 = atomicAdd(&c[d1.y], 1);
        int r6 = atomicAdd(&c[d1.z], 1);
        int r7 = atomicAdd(&c[d1.w], 1);
        *(int4*)(r + i0)     = make_int4(r0, r1, r2, r3);
        *(int4*)(r + i0 + 4) = make_int4(r4, r5, r6, r7);
    } else if (bid < 12990) {
        // ---- copyx: fp32 -> fp16, half4 per thread ----
        int i = (bid - 490) * 256 + tid;           // < 3,200,000 exact
        float4_ v = ((const float4_*)x)[i];
        half4_ h;
        h[0] = (_Float16)v[0]; h[1] = (_Float16)v[1];
        h[2] = (_Float16)v[2]; h[3] = (_Float16)v[3];
        ((half4_*)xh)[i] = h;
    } else if (bid < 14654) {
        // ---- wcat: [Wl|W0|W1] rows fp16, then Wout fp16 ----
        int i = (bid - 12990) * 256 + tid;         // < 425984 exact
        if (i < 2 * 256 * 768) {
            int l = i / (256 * 768);
            int r = i % (256 * 768);
            int j = r / 768, k = r % 768;
            const float* s = (k < 256) ? Wl : (k < 512 ? W0 : W1);
            Wcat[i] = (_Float16)s[l * 65536 + j * 256 + (k & 255)];
        } else {
            Wcat[i] = (_Float16)Wout[i - 2 * 256 * 768];
        }
    } else if (bid < 14690) {
        // ---- pad rows [N,NPAD) of xh, aggb, h1 ----
        int j = (bid - 14654) * 256 + tid;         // < 9216
        int buf = j / 3072, jj = j % 3072;
        _Float16* p = (buf == 0) ? xh : (buf == 1) ? aggb : h1;
        half4_ z = {(_Float16)0.f, (_Float16)0.f, (_Float16)0.f, (_Float16)0.f};
        *(half4_*)(p + (size_t)N_NODES * 256 + (size_t)jj * 4) = z;
    } else {
        int i = (bid - 14690) * 256 + tid;
        if (i < 512)      bias[i] = bl[i] + b0[i] + b1[i];
        else if (i < 640) bias[i] = bout[i - 512];
    }
}

// ================= decoupled-lookback scan =================
// 392 blocks: set = bid/196, seq = bid%196. state[set*196+seq] packs
// (status<<32)|value; status 1=aggregate, 2=inclusive. All cross-block
// traffic via 64-bit device-scope atomics (XCD-coherent).
__global__ __launch_bounds__(256) void scan_kernel(const int* __restrict__ cnt,
                                                   unsigned long long* __restrict__ state,
                                                   int* __restrict__ rp) {
    __shared__ int sm[256];
    __shared__ int s_excl;
    const int bid = blockIdx.x;
    const int set = bid / NSCAN;
    const int seq = bid % NSCAN;
    const int t = threadIdx.x;
    const int i = seq * 256 + t;
    const int* c = cnt + set * N_NODES;
    int* rpS = rp + set * (N_NODES + 1);
    unsigned long long* st = state + set * NSCAN;

    int v = (i < N_NODES) ? c[i] : 0;
    sm[t] = v;
    __syncthreads();
    for (int off = 1; off < 256; off <<= 1) {
        int x = sm[t];
        if (t >= off) x += sm[t - off];
        __syncthreads();
        sm[t] = x;
        __syncthreads();
    }
    int total = sm[255];

    if (t == 0) {
        if (seq == 0) {
            atomicExch(&st[0], (2ULL << 32) | (unsigned int)total);
            s_excl = 0;
        } else {
            atomicExch(&st[seq], (1ULL << 32) | (unsigned int)total);
            int running = 0;
            int j = seq - 1;
            while (true) {
                unsigned long long s = atomicAdd(&st[j], 0ULL);
                unsigned int tag = (unsigned int)(s >> 32);
                if (tag == 0) continue;           // not published yet
                running += (int)(unsigned int)s;
                if (tag == 2) break;
                j--;
            }
            atomicExch(&st[seq], (2ULL << 32) | (unsigned int)(running + total));
            s_excl = running;
        }
    }
    __syncthreads();
    int excl = s_excl;
    if (i < N_NODES) rpS[i] = sm[t] - v + excl;
    if (seq == NSCAN - 1 && t == 0) rpS[N_NODES] = excl + total;
}

// ================= atomic-free placement =================
__global__ void place_kernel(const int* __restrict__ e1, const int* __restrict__ e2,
                             const int* __restrict__ ranks, const int* __restrict__ rp,
                             int* __restrict__ col, int e, int n) {
    const int set = blockIdx.y;
    const int* ed = set ? e2 : e1;
    const int* r  = ranks + set * e;
    const int* rpS = rp + set * (n + 1);
    int* cl = col + set * e;
    int i0 = (blockIdx.x * 256 + threadIdx.x) * 8;
    if (i0 >= e) return;
    int4 d0 = *(const int4*)(ed + i0);
    int4 d1 = *(const int4*)(ed + i0 + 4);
    int4 s0 = *(const int4*)(ed + e + i0);
    int4 s1 = *(const int4*)(ed + e + i0 + 4);
    int4 k0 = *(const int4*)(r + i0);
    int4 k1 = *(const int4*)(r + i0 + 4);
    int p0 = rpS[d0.x] + k0.x;
    int p1 = rpS[d0.y] + k0.y;
    int p2 = rpS[d0.z] + k0.z;
    int p3 = rpS[d0.w] + k0.w;
    int p4 = rpS[d1.x] + k1.x;
    int p5 = rpS[d1.y] + k1.y;
    int p6 = rpS[d1.z] + k1.z;
    int p7 = rpS[d1.w] + k1.w;
    cl[p0] = s0.x; cl[p1] = s0.y; cl[p2] = s0.z; cl[p3] = s0.w;
    cl[p4] = s1.x; cl[p5] = s1.y; cl[p6] = s1.z; cl[p7] = s1.w;
}

// ================= CSR pull gather: split-wave, 16B/lane =================
__global__ void gather_kernel(const _Float16* __restrict__ hin,
                              const int* __restrict__ rowptr, const int* __restrict__ col,
                              _Float16* __restrict__ dst, int n) {
    int node = blockIdx.x * 4 + (threadIdx.x >> 6);
    int lane = threadIdx.x & 63;
    int half = lane >> 5, l5 = lane & 31;
    if (node >= n) return;
    int s = rowptr[node], e = rowptr[node + 1];
    float a[8] = {0.f, 0.f, 0.f, 0.f, 0.f, 0.f, 0.f, 0.f};
    float b[8] = {0.f, 0.f, 0.f, 0.f, 0.f, 0.f, 0.f, 0.f};
    int i = s + half;
    for (; i + 2 < e; i += 4) {
        int c0 = col[i], c1 = col[i + 2];
        half8_ v0 = *(const half8_*)(hin + (size_t)c0 * 256 + l5 * 8);
        half8_ v1 = *(const half8_*)(hin + (size_t)c1 * 256 + l5 * 8);
#pragma unroll
        for (int j = 0; j < 8; j++) { a[j] += (float)v0[j]; b[j] += (float)v1[j]; }
    }
    for (; i < e; i += 2) {
        int c0 = col[i];
        half8_ v0 = *(const half8_*)(hin + (size_t)c0 * 256 + l5 * 8);
#pragma unroll
        for (int j = 0; j < 8; j++) a[j] += (float)v0[j];
    }
    half8_ o;
#pragma unroll
    for (int j = 0; j < 8; j++) {
        float t = a[j] + b[j];
        t += __shfl_xor(t, 32, 64);
        o[j] = (_Float16)t;
    }
    if (half == 0)
        *(half8_*)(dst + (size_t)node * 256 + l5 * 8) = o;
}

// ================= fused layer GEMM (+optional output GEMM) =================
// H = LN(relu([agg|h|x] @ W^T + bias)); OUTFUSE: d_out = H @ Wout^T + bout
// directly from the LDS H tile (h2 never materialized).
template <bool OUTFUSE>
__global__ __launch_bounds__(512) void gemm_ln(const _Float16* __restrict__ agg,
                                               const _Float16* __restrict__ hsrc,
                                               const _Float16* __restrict__ xh,
                                               const _Float16* __restrict__ Bw,   // [256][768]
                                               const float* __restrict__ bias,    // layer 256 | out at +512... full array
                                               const float* __restrict__ gamma,
                                               const float* __restrict__ beta,
                                               _Float16* __restrict__ H,          // layer-1 out (unused if OUTFUSE)
                                               const _Float16* __restrict__ WoutH,// [128][256] fp16
                                               const float* __restrict__ biasOut, // [128]
                                               float* __restrict__ Out) {         // [N][128] fp32
    __shared__ __align__(16) char smem[49152];   // As 16K | Bs 32K
    char* AsB = smem;
    char* BsB = smem + 16384;
    const int rowBase = blockIdx.x * 128;
    const int tid  = threadIdx.x;
    const int lane = tid & 63;
    const int w    = tid >> 6;
    const int wm = w & 1, wn = w >> 1;
    const int quad = lane >> 4, mr = lane & 15;
    const int x7 = mr & 7;

    float4_ acc[4][4];
#pragma unroll
    for (int i = 0; i < 4; i++)
#pragma unroll
        for (int j = 0; j < 4; j++) { float4_ z4 = {0.f, 0.f, 0.f, 0.f}; acc[i][j] = z4; }

    int cA0 = w * 64 + lane, cA1 = cA0 + 512;
    int rA0 = cA0 >> 3, rA1 = cA1 >> 3;
    size_t offA0 = (size_t)(rowBase + rA0) * 256 + (((cA0 & 7) ^ (rA0 & 7)) * 8);
    size_t offA1 = (size_t)(rowBase + rA1) * 256 + (((cA1 & 7) ^ (rA1 & 7)) * 8);
    size_t offB[4];
#pragma unroll
    for (int j = 0; j < 4; j++) {
        int c = j * 512 + w * 64 + lane;
        int r = c >> 3;
        offB[j] = (size_t)r * 768 + (((c & 7) ^ (r & 7)) * 8);
    }
    void* lA0 = AsB + w * 1024;
    void* lA1 = AsB + 8192 + w * 1024;

    for (int k0 = 0; k0 < 768; k0 += 64) {
        const _Float16* src = (k0 < 256) ? agg : (k0 < 512) ? hsrc : xh;
        const int kloc = k0 & 255;
        gload16(src + offA0 + kloc, lA0);
        gload16(src + offA1 + kloc, lA1);
        gload16(Bw + offB[0] + k0, BsB + w * 1024);
        gload16(Bw + offB[1] + k0, BsB + 8192 + w * 1024);
        gload16(Bw + offB[2] + k0, BsB + 16384 + w * 1024);
        gload16(Bw + offB[3] + k0, BsB + 24576 + w * 1024);
        __syncthreads();
#pragma unroll
        for (int s = 0; s < 2; s++) {
            half8_ a[4], b[4];
#pragma unroll
            for (int im = 0; im < 4; im++) {
                int row = wm * 64 + im * 16 + mr;
                a[im] = *(const half8_*)(AsB + row * 128 + (((s * 4 + quad) ^ x7) * 16));
            }
#pragma unroll
            for (int in = 0; in < 4; in++) {
                int row = wn * 64 + in * 16 + mr;
                b[in] = *(const half8_*)(BsB + row * 128 + (((s * 4 + quad) ^ x7) * 16));
            }
#pragma unroll
            for (int im = 0; im < 4; im++)
#pragma unroll
                for (int in = 0; in < 4; in++)
                    acc[im][in] = __builtin_amdgcn_mfma_f32_16x16x32_f16(a[im], b[in], acc[im][in], 0, 0, 0);
        }
        __syncthreads();
    }

    float bv[4], gv[4], bev[4];
#pragma unroll
    for (int in = 0; in < 4; in++) {
        int colg = wn * 64 + in * 16 + mr;
        bv[in]  = bias[colg];
        gv[in]  = gamma[colg];
        bev[in] = beta[colg];
    }
    float* lnbuf   = (float*)AsB;
    float* lnstats = (float*)(AsB + 4096);

#pragma unroll
    for (int im = 0; im < 4; im++)
#pragma unroll
        for (int r = 0; r < 4; r++) {
            float s = 0.f, sq = 0.f;
#pragma unroll
            for (int in = 0; in < 4; in++) {
                float v = acc[im][in][r] + bv[in];
                v = v > 0.f ? v : 0.f;
                s += v; sq += v * v;
            }
            s  += __shfl_xor(s, 1, 64);  sq += __shfl_xor(sq, 1, 64);
            s  += __shfl_xor(s, 2, 64);  sq += __shfl_xor(sq, 2, 64);
            s  += __shfl_xor(s, 4, 64);  sq += __shfl_xor(sq, 4, 64);
            s  += __shfl_xor(s, 8, 64);  sq += __shfl_xor(sq, 8, 64);
            if (mr == 0) {
                int rl = wm * 64 + im * 16 + quad * 4 + r;
                lnbuf[(wn * 128 + rl) * 2]     = s;
                lnbuf[(wn * 128 + rl) * 2 + 1] = sq;
            }
        }
    __syncthreads();
    if (tid < 128) {
        float s  = lnbuf[tid * 2]             + lnbuf[(128 + tid) * 2]
                 + lnbuf[(256 + tid) * 2]     + lnbuf[(384 + tid) * 2];
        float sq = lnbuf[tid * 2 + 1]         + lnbuf[(128 + tid) * 2 + 1]
                 + lnbuf[(256 + tid) * 2 + 1] + lnbuf[(384 + tid) * 2 + 1];
        float mu  = s * (1.0f / 256.0f);
        float var = sq * (1.0f / 256.0f) - mu * mu;
        lnstats[tid * 2]     = mu;
        lnstats[tid * 2 + 1] = rsqrtf(var + EPS);
    }
    __syncthreads();

    float bvo[4];
    if (OUTFUSE) {
#pragma unroll
        for (int ct = 0; ct < 4; ct++)
            bvo[ct] = biasOut[(w >> 2) * 64 + ct * 16 + mr];
    }

    _Float16* BsH = (_Float16*)BsB;   // [64 rows][256 cols], chunk-swizzled
#pragma unroll
    for (int p = 0; p < 2; p++) {
        if (wm == p) {
#pragma unroll
            for (int im = 0; im < 4; im++)
#pragma unroll
                for (int r = 0; r < 4; r++) {
                    int rl = im * 16 + quad * 4 + r;
                    float mu = lnstats[(p * 64 + rl) * 2];
                    float rs = lnstats[(p * 64 + rl) * 2 + 1];
#pragma unroll
                    for (int in = 0; in < 4; in++) {
                        float v = acc[im][in][r] + bv[in];
                        v = v > 0.f ? v : 0.f;
                        int colg = wn * 64 + in * 16 + mr;
                        int off2 = rl * 256 + (((colg >> 3) ^ (rl & 31)) << 3) + (colg & 7);
                        BsH[off2] = (_Float16)((v - mu) * rs * gv[in] + bev[in]);
                    }
                }
        }
        __syncthreads();
        if (!OUTFUSE) {
            // store H rows to global (layer-1 path)
#pragma unroll
            for (int i = 0; i < 4; i++) {
                int c = i * 512 + tid;
                int row = c >> 5, ch = c & 31;
                half8_ v = *(const half8_*)(BsB + row * 512 + ((ch ^ (row & 31)) << 4));
                *(half8_*)(H + (size_t)(rowBase + p * 64 + row) * 256 + ch * 8) = v;
            }
        } else {
            // out-GEMM: 64 rows x 128 cols, K=256, from swizzled BsH + global Wout
            const int rt = w & 3;          // row tile (16 rows)
            const int chh = w >> 2;        // col half (64 cols)
            float4_ acc2[4];
#pragma unroll
            for (int ct = 0; ct < 4; ct++) { float4_ z4 = {0.f, 0.f, 0.f, 0.f}; acc2[ct] = z4; }
            const int rA = rt * 16 + mr;
#pragma unroll
            for (int s2 = 0; s2 < 8; s2++) {
                int ck = s2 * 4 + quad;
                half8_ a2 = *(const half8_*)(BsB + rA * 512 + ((ck ^ (rA & 31)) << 4));
#pragma unroll
                for (int ct = 0; ct < 4; ct++) {
                    int colg = chh * 64 + ct * 16 + mr;
                    half8_ b2 = *(const half8_*)(WoutH + (size_t)colg * 256 + s2 * 32 + quad * 8);
                    acc2[ct] = __builtin_amdgcn_mfma_f32_16x16x32_f16(a2, b2, acc2[ct], 0, 0, 0);
                }
            }
#pragma unroll
            for (int ct = 0; ct < 4; ct++) {
                int colg = chh * 64 + ct * 16 + mr;
#pragma unroll
                for (int r = 0; r < 4; r++) {
                    int row = rowBase + p * 64 + rt * 16 + quad * 4 + r;
                    if (row < N_NODES)
                        Out[(size_t)row * 128 + colg] = acc2[ct][r] + bvo[ct];
                }
            }
        }
        __syncthreads();
    }
}

extern "C" void kernel_launch(void* const* d_in, const int* in_sizes, int n_in,
                              void* d_out, int out_size, void* d_ws, size_t ws_size,
                              hipStream_t stream) {
    const float* x    = (const float*)d_in[0];
    const int*   e1   = (const int*)d_in[1];
    const int*   e2   = (const int*)d_in[2];
    const float* Wl   = (const float*)d_in[3];
    const float* bl   = (const float*)d_in[4];
    const float* W0   = (const float*)d_in[5];
    const float* b0   = (const float*)d_in[6];
    const float* W1   = (const float*)d_in[7];
    const float* b1   = (const float*)d_in[8];
    const float* gamma= (const float*)d_in[9];
    const float* beta = (const float*)d_in[10];
    const float* Wout = (const float*)d_in[11];
    const float* bout = (const float*)d_in[12];

    char* ws = (char*)d_ws;
    size_t off = 0;
    auto alloc = [&](size_t bytes) -> char* {
        char* p = ws + off;
        off = (off + bytes + 255) & ~(size_t)255;
        return p;
    };
    _Float16* xh   = (_Float16*)alloc((size_t)NPAD * 256 * 2);
    _Float16* aggb = (_Float16*)alloc((size_t)NPAD * 256 * 2);
    _Float16* h1   = (_Float16*)alloc((size_t)NPAD * 256 * 2);
    _Float16* Wcat = (_Float16*)alloc((size_t)(2 * 256 * 768 + 128 * 256) * 2);
    float*    bias = (float*)alloc(640 * 4);
    int* cnt   = (int*)alloc((size_t)2 * N_NODES * 4);
    unsigned long long* states = (unsigned long long*)alloc((size_t)2 * NSCAN * 8);
    int* rp    = (int*)alloc((size_t)2 * (N_NODES + 1) * 4);
    int* ranks = (int*)alloc((size_t)2 * N_EDGES * 4);
    int* col   = (int*)alloc((size_t)2 * N_EDGES * 4);

    int* rp1 = rp, *rp2 = rp + (N_NODES + 1);
    int* col1 = col, *col2 = col + N_EDGES;

    // zero cnt + lookback states in one shot (contiguous region)
    size_t zbytes = (size_t)((char*)states + 2 * NSCAN * 8 - (char*)cnt);
    hipMemsetAsync(cnt, 0, zbytes, stream);

    prep_kernel<<<14693, 256, 0, stream>>>(e1, e2, cnt, ranks, x, xh, aggb, h1,
                                           Wl, W0, W1, Wout, Wcat,
                                           bl, b0, b1, bout, bias);
    scan_kernel<<<2 * NSCAN, 256, 0, stream>>>(cnt, states, rp);
    const int eb8 = (N_EDGES / 8 + 255) / 256;   // 245
    place_kernel<<<dim3(eb8, 2), 256, 0, stream>>>(e1, e2, ranks, rp, col, N_EDGES, N_NODES);

    const int nb4 = (N_NODES + 3) / 4;
    const _Float16* WoutH = Wcat + 393216;

    // layer 1: weights idx 1, edges r2, h_in = x
    gather_kernel<<<nb4, 256, 0, stream>>>(xh, rp2, col2, aggb, N_NODES);
    gemm_ln<false><<<391, 512, 0, stream>>>(aggb, xh, xh, Wcat + 196608,
                                            bias + 256, gamma + 256, beta + 256, h1,
                                            nullptr, nullptr, nullptr);
    // layer 2 + fused output GEMM
    gather_kernel<<<nb4, 256, 0, stream>>>(h1, rp1, col1, aggb, N_NODES);
    gemm_ln<true><<<391, 512, 0, stream>>>(aggb, h1, xh, Wcat,
                                           bias, gamma, beta, nullptr,
                                           WoutH, bias + 512, (float*)d_out);
}

// Round 9
// 345.384 us; speedup vs baseline: 1.0739x; 1.0739x over previous
//
#include <hip/hip_runtime.h>
#include <stdint.h>

#define N_NODES 50000
#define N_EDGES 500000
#define NPAD    50048   // 391 * 128
#define NSCAN   196     // ceil(50000/256)
#define EPS     1e-5f

typedef _Float16 half8_ __attribute__((ext_vector_type(8)));
typedef _Float16 half4_ __attribute__((ext_vector_type(4)));
typedef float    float4_ __attribute__((ext_vector_type(4)));

typedef uint32_t u32_g __attribute__((address_space(1)));
typedef uint32_t u32_s __attribute__((address_space(3)));

__device__ __forceinline__ void gload16(const void* g, void* lds_wave_base) {
    __builtin_amdgcn_global_load_lds((const u32_g*)g, (u32_s*)lds_wave_base, 16, 0, 0);
}

// ================= mega prep kernel =================
// block ranges: [0,490) count_rank | [490,12990) copyx | [12990,14654) wcat
//               [14654,14690) pad  | [14690,14693) bias
__global__ __launch_bounds__(256) void prep_kernel(
        const int* __restrict__ e1, const int* __restrict__ e2,
        int* __restrict__ cnt, int* __restrict__ ranks,
        const float* __restrict__ x, _Float16* __restrict__ xh,
        _Float16* __restrict__ aggb, _Float16* __restrict__ h1,
        const float* __restrict__ Wl, const float* __restrict__ W0,
        const float* __restrict__ W1, const float* __restrict__ Wout,
        _Float16* __restrict__ Wcat,
        const float* __restrict__ bl, const float* __restrict__ b0,
        const float* __restrict__ b1, const float* __restrict__ bout,
        float* __restrict__ bias) {
    const int bid = blockIdx.x;
    const int tid = threadIdx.x;
    if (bid < 490) {
        // ---- count_rank: 8 edges/thread, atomic return = rank ----
        const int set = (bid >= 245);
        const int bx  = set ? bid - 245 : bid;
        const int* dst = set ? e2 : e1;
        int* c = cnt + set * N_NODES;
        int* r = ranks + set * N_EDGES;
        int i0 = (bx * 256 + tid) * 8;
        if (i0 >= N_EDGES) return;
        int4 d0 = *(const int4*)(dst + i0);
        int4 d1 = *(const int4*)(dst + i0 + 4);
        int r0 = atomicAdd(&c[d0.x], 1);
        int r1 = atomicAdd(&c[d0.y], 1);
        int r2 = atomicAdd(&c[d0.z], 1);
        int r3 = atomicAdd(&c[d0.w], 1);
        int r4 = atomicAdd(&c[d1.x], 1);
        int r5 = atomicAdd(&c[d1.y], 1);
        int r6 = atomicAdd(&c[d1.z], 1);
        int r7 = atomicAdd(&c[d1.w], 1);
        *(int4*)(r + i0)     = make_int4(r0, r1, r2, r3);
        *(int4*)(r + i0 + 4) = make_int4(r4, r5, r6, r7);
    } else if (bid < 12990) {
        // ---- copyx: fp32 -> fp16 ----
        int i = (bid - 490) * 256 + tid;           // < 3,200,000 exact
        float4_ v = ((const float4_*)x)[i];
        half4_ h;
        h[0] = (_Float16)v[0]; h[1] = (_Float16)v[1];
        h[2] = (_Float16)v[2]; h[3] = (_Float16)v[3];
        ((half4_*)xh)[i] = h;
    } else if (bid < 14654) {
        // ---- wcat: [Wl|W0|W1] rows fp16, then Wout fp16 ----
        int i = (bid - 12990) * 256 + tid;         // < 425984 exact
        if (i < 2 * 256 * 768) {
            int l = i / (256 * 768);
            int r = i % (256 * 768);
            int j = r / 768, k = r % 768;
            const float* s = (k < 256) ? Wl : (k < 512 ? W0 : W1);
            Wcat[i] = (_Float16)s[l * 65536 + j * 256 + (k & 255)];
        } else {
            Wcat[i] = (_Float16)Wout[i - 2 * 256 * 768];
        }
    } else if (bid < 14690) {
        // ---- pad rows [N,NPAD) of xh, aggb, h1 ----
        int j = (bid - 14654) * 256 + tid;         // < 9216
        int buf = j / 3072, jj = j % 3072;
        _Float16* p = (buf == 0) ? xh : (buf == 1) ? aggb : h1;
        half4_ z = {(_Float16)0.f, (_Float16)0.f, (_Float16)0.f, (_Float16)0.f};
        *(half4_*)(p + (size_t)N_NODES * 256 + (size_t)jj * 4) = z;
    } else {
        int i = (bid - 14690) * 256 + tid;
        if (i < 512)      bias[i] = bl[i] + b0[i] + b1[i];
        else if (i < 640) bias[i] = bout[i - 512];
    }
}

// ================= decoupled-lookback scan =================
__global__ __launch_bounds__(256) void scan_kernel(const int* __restrict__ cnt,
                                                   unsigned long long* __restrict__ state,
                                                   int* __restrict__ rp) {
    __shared__ int sm[256];
    __shared__ int s_excl;
    const int bid = blockIdx.x;
    const int set = bid / NSCAN;
    const int seq = bid % NSCAN;
    const int t = threadIdx.x;
    const int i = seq * 256 + t;
    const int* c = cnt + set * N_NODES;
    int* rpS = rp + set * (N_NODES + 1);
    unsigned long long* st = state + set * NSCAN;

    int v = (i < N_NODES) ? c[i] : 0;
    sm[t] = v;
    __syncthreads();
    for (int off = 1; off < 256; off <<= 1) {
        int x = sm[t];
        if (t >= off) x += sm[t - off];
        __syncthreads();
        sm[t] = x;
        __syncthreads();
    }
    int total = sm[255];

    if (t == 0) {
        if (seq == 0) {
            atomicExch(&st[0], (2ULL << 32) | (unsigned int)total);
            s_excl = 0;
        } else {
            atomicExch(&st[seq], (1ULL << 32) | (unsigned int)total);
            int running = 0;
            int j = seq - 1;
            while (true) {
                unsigned long long s = atomicAdd(&st[j], 0ULL);
                unsigned int tag = (unsigned int)(s >> 32);
                if (tag == 0) continue;
                running += (int)(unsigned int)s;
                if (tag == 2) break;
                j--;
            }
            atomicExch(&st[seq], (2ULL << 32) | (unsigned int)(running + total));
            s_excl = running;
        }
    }
    __syncthreads();
    int excl = s_excl;
    if (i < N_NODES) rpS[i] = sm[t] - v + excl;
    if (seq == NSCAN - 1 && t == 0) rpS[N_NODES] = excl + total;
}

// ================= atomic-free placement =================
__global__ void place_kernel(const int* __restrict__ e1, const int* __restrict__ e2,
                             const int* __restrict__ ranks, const int* __restrict__ rp,
                             int* __restrict__ col, int e, int n) {
    const int set = blockIdx.y;
    const int* ed = set ? e2 : e1;
    const int* r  = ranks + set * e;
    const int* rpS = rp + set * (n + 1);
    int* cl = col + set * e;
    int i0 = (blockIdx.x * 256 + threadIdx.x) * 8;
    if (i0 >= e) return;
    int4 d0 = *(const int4*)(ed + i0);
    int4 d1 = *(const int4*)(ed + i0 + 4);
    int4 s0 = *(const int4*)(ed + e + i0);
    int4 s1 = *(const int4*)(ed + e + i0 + 4);
    int4 k0 = *(const int4*)(r + i0);
    int4 k1 = *(const int4*)(r + i0 + 4);
    int p0 = rpS[d0.x] + k0.x;
    int p1 = rpS[d0.y] + k0.y;
    int p2 = rpS[d0.z] + k0.z;
    int p3 = rpS[d0.w] + k0.w;
    int p4 = rpS[d1.x] + k1.x;
    int p5 = rpS[d1.y] + k1.y;
    int p6 = rpS[d1.z] + k1.z;
    int p7 = rpS[d1.w] + k1.w;
    cl[p0] = s0.x; cl[p1] = s0.y; cl[p2] = s0.z; cl[p3] = s0.w;
    cl[p4] = s1.x; cl[p5] = s1.y; cl[p6] = s1.z; cl[p7] = s1.w;
}

// ================= CSR pull gather: split-wave, 16B/lane, 8 rows in flight =========
__global__ void gather_kernel(const _Float16* __restrict__ hin,
                              const int* __restrict__ rowptr, const int* __restrict__ col,
                              _Float16* __restrict__ dst, int n) {
    int node = blockIdx.x * 4 + (threadIdx.x >> 6);
    int lane = threadIdx.x & 63;
    int half = lane >> 5, l5 = lane & 31;
    if (node >= n) return;
    int s = rowptr[node], e = rowptr[node + 1];
    float a[8] = {0.f, 0.f, 0.f, 0.f, 0.f, 0.f, 0.f, 0.f};
    float b[8] = {0.f, 0.f, 0.f, 0.f, 0.f, 0.f, 0.f, 0.f};
    int i = s + half;
    // each half strides 2; unroll 4 -> 4 independent row loads in flight
    for (; i + 6 < e; i += 8) {
        int c0 = col[i], c1 = col[i + 2], c2 = col[i + 4], c3 = col[i + 6];
        half8_ v0 = *(const half8_*)(hin + (size_t)c0 * 256 + l5 * 8);
        half8_ v1 = *(const half8_*)(hin + (size_t)c1 * 256 + l5 * 8);
        half8_ v2 = *(const half8_*)(hin + (size_t)c2 * 256 + l5 * 8);
        half8_ v3 = *(const half8_*)(hin + (size_t)c3 * 256 + l5 * 8);
#pragma unroll
        for (int j = 0; j < 8; j++) {
            a[j] += (float)v0[j] + (float)v2[j];
            b[j] += (float)v1[j] + (float)v3[j];
        }
    }
    for (; i < e; i += 2) {
        int c0 = col[i];
        half8_ v0 = *(const half8_*)(hin + (size_t)c0 * 256 + l5 * 8);
#pragma unroll
        for (int j = 0; j < 8; j++) a[j] += (float)v0[j];
    }
    half8_ o;
#pragma unroll
    for (int j = 0; j < 8; j++) {
        float t = a[j] + b[j];
        t += __shfl_xor(t, 32, 64);
        o[j] = (_Float16)t;
    }
    if (half == 0)
        *(half8_*)(dst + (size_t)node * 256 + l5 * 8) = o;
}

// ================= fused layer GEMM: H = LN(relu([agg|h|x] @ W^T + bias)) =========
__global__ __launch_bounds__(512) void gemm_ln(const _Float16* __restrict__ agg,
                                               const _Float16* __restrict__ hsrc,
                                               const _Float16* __restrict__ xh,
                                               const _Float16* __restrict__ Bw,  // [256][768]
                                               const float* __restrict__ bias,
                                               const float* __restrict__ gamma,
                                               const float* __restrict__ beta,
                                               _Float16* __restrict__ H) {
    __shared__ __align__(16) char smem[49152];   // As 16K | Bs 32K
    char* AsB = smem;
    char* BsB = smem + 16384;
    const int rowBase = blockIdx.x * 128;
    const int tid  = threadIdx.x;
    const int lane = tid & 63;
    const int w    = tid >> 6;
    const int wm = w & 1, wn = w >> 1;
    const int quad = lane >> 4, mr = lane & 15;
    const int x7 = mr & 7;

    float4_ acc[4][4];
#pragma unroll
    for (int i = 0; i < 4; i++)
#pragma unroll
        for (int j = 0; j < 4; j++) { float4_ z4 = {0.f, 0.f, 0.f, 0.f}; acc[i][j] = z4; }

    int cA0 = w * 64 + lane, cA1 = cA0 + 512;
    int rA0 = cA0 >> 3, rA1 = cA1 >> 3;
    size_t offA0 = (size_t)(rowBase + rA0) * 256 + (((cA0 & 7) ^ (rA0 & 7)) * 8);
    size_t offA1 = (size_t)(rowBase + rA1) * 256 + (((cA1 & 7) ^ (rA1 & 7)) * 8);
    size_t offB[4];
#pragma unroll
    for (int j = 0; j < 4; j++) {
        int c = j * 512 + w * 64 + lane;
        int r = c >> 3;
        offB[j] = (size_t)r * 768 + (((c & 7) ^ (r & 7)) * 8);
    }
    void* lA0 = AsB + w * 1024;
    void* lA1 = AsB + 8192 + w * 1024;

    for (int k0 = 0; k0 < 768; k0 += 64) {
        const _Float16* src = (k0 < 256) ? agg : (k0 < 512) ? hsrc : xh;
        const int kloc = k0 & 255;
        gload16(src + offA0 + kloc, lA0);
        gload16(src + offA1 + kloc, lA1);
        gload16(Bw + offB[0] + k0, BsB + w * 1024);
        gload16(Bw + offB[1] + k0, BsB + 8192 + w * 1024);
        gload16(Bw + offB[2] + k0, BsB + 16384 + w * 1024);
        gload16(Bw + offB[3] + k0, BsB + 24576 + w * 1024);
        __syncthreads();
#pragma unroll
        for (int s = 0; s < 2; s++) {
            half8_ a[4], b[4];
#pragma unroll
            for (int im = 0; im < 4; im++) {
                int row = wm * 64 + im * 16 + mr;
                a[im] = *(const half8_*)(AsB + row * 128 + (((s * 4 + quad) ^ x7) * 16));
            }
#pragma unroll
            for (int in = 0; in < 4; in++) {
                int row = wn * 64 + in * 16 + mr;
                b[in] = *(const half8_*)(BsB + row * 128 + (((s * 4 + quad) ^ x7) * 16));
            }
#pragma unroll
            for (int im = 0; im < 4; im++)
#pragma unroll
                for (int in = 0; in < 4; in++)
                    acc[im][in] = __builtin_amdgcn_mfma_f32_16x16x32_f16(a[im], b[in], acc[im][in], 0, 0, 0);
        }
        __syncthreads();
    }

    float bv[4], gv[4], bev[4];
#pragma unroll
    for (int in = 0; in < 4; in++) {
        int colg = wn * 64 + in * 16 + mr;
        bv[in]  = bias[colg];
        gv[in]  = gamma[colg];
        bev[in] = beta[colg];
    }
    float* lnbuf   = (float*)AsB;
    float* lnstats = (float*)(AsB + 4096);

#pragma unroll
    for (int im = 0; im < 4; im++)
#pragma unroll
        for (int r = 0; r < 4; r++) {
            float s = 0.f, sq = 0.f;
#pragma unroll
            for (int in = 0; in < 4; in++) {
                float v = acc[im][in][r] + bv[in];
                v = v > 0.f ? v : 0.f;
                s += v; sq += v * v;
            }
            s  += __shfl_xor(s, 1, 64);  sq += __shfl_xor(sq, 1, 64);
            s  += __shfl_xor(s, 2, 64);  sq += __shfl_xor(sq, 2, 64);
            s  += __shfl_xor(s, 4, 64);  sq += __shfl_xor(sq, 4, 64);
            s  += __shfl_xor(s, 8, 64);  sq += __shfl_xor(sq, 8, 64);
            if (mr == 0) {
                int rl = wm * 64 + im * 16 + quad * 4 + r;
                lnbuf[(wn * 128 + rl) * 2]     = s;
                lnbuf[(wn * 128 + rl) * 2 + 1] = sq;
            }
        }
    __syncthreads();
    if (tid < 128) {
        float s  = lnbuf[tid * 2]             + lnbuf[(128 + tid) * 2]
                 + lnbuf[(256 + tid) * 2]     + lnbuf[(384 + tid) * 2];
        float sq = lnbuf[tid * 2 + 1]         + lnbuf[(128 + tid) * 2 + 1]
                 + lnbuf[(256 + tid) * 2 + 1] + lnbuf[(384 + tid) * 2 + 1];
        float mu  = s * (1.0f / 256.0f);
        float var = sq * (1.0f / 256.0f) - mu * mu;
        lnstats[tid * 2]     = mu;
        lnstats[tid * 2 + 1] = rsqrtf(var + EPS);
    }
    __syncthreads();

    _Float16* BsH = (_Float16*)BsB;
#pragma unroll
    for (int p = 0; p < 2; p++) {
        if (wm == p) {
#pragma unroll
            for (int im = 0; im < 4; im++)
#pragma unroll
                for (int r = 0; r < 4; r++) {
                    int rl = im * 16 + quad * 4 + r;
                    float mu = lnstats[(p * 64 + rl) * 2];
                    float rs = lnstats[(p * 64 + rl) * 2 + 1];
#pragma unroll
                    for (int in = 0; in < 4; in++) {
                        float v = acc[im][in][r] + bv[in];
                        v = v > 0.f ? v : 0.f;
                        BsH[rl * 256 + wn * 64 + in * 16 + mr] =
                            (_Float16)((v - mu) * rs * gv[in] + bev[in]);
                    }
                }
        }
        __syncthreads();
#pragma unroll
        for (int i = 0; i < 4; i++) {
            int c = i * 512 + tid;
            int row = c >> 5, ch = c & 31;
            half8_ v = *(const half8_*)(BsB + c * 16);
            *(half8_*)(H + (size_t)(rowBase + p * 64 + row) * 256 + ch * 8) = v;
        }
        __syncthreads();
    }
}

// ================= final GEMM: d_out = h2 @ Wout^T + bout (fp32) =================
__global__ __launch_bounds__(256) void gemm_bt(const _Float16* __restrict__ A, int lda,
                                               const _Float16* __restrict__ B, int ldb,
                                               const float* __restrict__ bias,
                                               float* __restrict__ C, int ldc,
                                               int K, int Mstore) {
    __shared__ _Float16 As[128 * 32];
    __shared__ _Float16 Bs[128 * 32];
    const int rowBase = blockIdx.x * 128;
    const int colBase = blockIdx.y * 128;
    const int tid  = threadIdx.x;
    const int lane = tid & 63;
    const int w    = tid >> 6;
    const int wm = w & 1, wn = w >> 1;
    const int quad = lane >> 4, mr = lane & 15;

    float4_ acc[4][4];
#pragma unroll
    for (int i = 0; i < 4; i++)
#pragma unroll
        for (int j = 0; j < 4; j++) { float4_ z4 = {0.f, 0.f, 0.f, 0.f}; acc[i][j] = z4; }

    const int c0  = w * 64 + lane;
    const int rA0 = c0 >> 2;
    const int ko  = (c0 & 3) * 8;
    char* AsB = (char*)As;
    char* BsB = (char*)Bs;
    void* lA0 = AsB + w * 1024;
    void* lA1 = AsB + 4096 + w * 1024;
    void* lB0 = BsB + w * 1024;
    void* lB1 = BsB + 4096 + w * 1024;
    const _Float16* gA0 = A + (size_t)(rowBase + rA0) * lda + ko;
    const _Float16* gA1 = gA0 + (size_t)64 * lda;
    const _Float16* gB0 = B + (size_t)(colBase + rA0) * ldb + ko;
    const _Float16* gB1 = gB0 + (size_t)64 * ldb;

    for (int k0 = 0; k0 < K; k0 += 32) {
        gload16(gA0 + k0, lA0);
        gload16(gA1 + k0, lA1);
        gload16(gB0 + k0, lB0);
        gload16(gB1 + k0, lB1);
        __syncthreads();
        half8_ a[4], b[4];
#pragma unroll
        for (int im = 0; im < 4; im++)
            a[im] = *(const half8_*)(AsB + ((wm * 64 + im * 16 + mr) * 64 + quad * 16));
#pragma unroll
        for (int in = 0; in < 4; in++)
            b[in] = *(const half8_*)(BsB + ((wn * 64 + in * 16 + mr) * 64 + quad * 16));
#pragma unroll
        for (int im = 0; im < 4; im++)
#pragma unroll
            for (int in = 0; in < 4; in++)
                acc[im][in] = __builtin_amdgcn_mfma_f32_16x16x32_f16(a[im], b[in], acc[im][in], 0, 0, 0);
        __syncthreads();
    }

#pragma unroll
    for (int in = 0; in < 4; in++) {
        const int colg = colBase + wn * 64 + in * 16 + mr;
        const float bv = bias[colg];
#pragma unroll
        for (int im = 0; im < 4; im++) {
            float4_ c = acc[im][in];
#pragma unroll
            for (int r = 0; r < 4; r++) {
                int row = rowBase + wm * 64 + im * 16 + quad * 4 + r;
                if (row < Mstore) C[(size_t)row * ldc + colg] = c[r] + bv;
            }
        }
    }
}

extern "C" void kernel_launch(void* const* d_in, const int* in_sizes, int n_in,
                              void* d_out, int out_size, void* d_ws, size_t ws_size,
                              hipStream_t stream) {
    const float* x    = (const float*)d_in[0];
    const int*   e1   = (const int*)d_in[1];
    const int*   e2   = (const int*)d_in[2];
    const float* Wl   = (const float*)d_in[3];
    const float* bl   = (const float*)d_in[4];
    const float* W0   = (const float*)d_in[5];
    const float* b0   = (const float*)d_in[6];
    const float* W1   = (const float*)d_in[7];
    const float* b1   = (const float*)d_in[8];
    const float* gamma= (const float*)d_in[9];
    const float* beta = (const float*)d_in[10];
    const float* Wout = (const float*)d_in[11];
    const float* bout = (const float*)d_in[12];

    char* ws = (char*)d_ws;
    size_t off = 0;
    auto alloc = [&](size_t bytes) -> char* {
        char* p = ws + off;
        off = (off + bytes + 255) & ~(size_t)255;
        return p;
    };
    _Float16* xh   = (_Float16*)alloc((size_t)NPAD * 256 * 2);
    _Float16* aggb = (_Float16*)alloc((size_t)NPAD * 256 * 2);
    _Float16* h1   = (_Float16*)alloc((size_t)NPAD * 256 * 2);
    _Float16* h2   = (_Float16*)alloc((size_t)NPAD * 256 * 2);
    _Float16* Wcat = (_Float16*)alloc((size_t)(2 * 256 * 768 + 128 * 256) * 2);
    float*    bias = (float*)alloc(640 * 4);
    int* cnt   = (int*)alloc((size_t)2 * N_NODES * 4);
    unsigned long long* states = (unsigned long long*)alloc((size_t)2 * NSCAN * 8);
    int* rp    = (int*)alloc((size_t)2 * (N_NODES + 1) * 4);
    int* ranks = (int*)alloc((size_t)2 * N_EDGES * 4);
    int* col   = (int*)alloc((size_t)2 * N_EDGES * 4);

    int* rp1 = rp, *rp2 = rp + (N_NODES + 1);
    int* col1 = col, *col2 = col + N_EDGES;

    // zero cnt + lookback states in one shot (contiguous region)
    size_t zbytes = (size_t)((char*)states + 2 * NSCAN * 8 - (char*)cnt);
    hipMemsetAsync(cnt, 0, zbytes, stream);

    prep_kernel<<<14693, 256, 0, stream>>>(e1, e2, cnt, ranks, x, xh, aggb, h1,
                                           Wl, W0, W1, Wout, Wcat,
                                           bl, b0, b1, bout, bias);
    scan_kernel<<<2 * NSCAN, 256, 0, stream>>>(cnt, states, rp);
    const int eb8 = (N_EDGES / 8 + 255) / 256;   // 245
    place_kernel<<<dim3(eb8, 2), 256, 0, stream>>>(e1, e2, ranks, rp, col, N_EDGES, N_NODES);

    const int nb4 = (N_NODES + 3) / 4;
    const _Float16* WoutH = Wcat + 393216;

    // layer 1: weights idx 1, edges r2, h_in = x
    gather_kernel<<<nb4, 256, 0, stream>>>(xh, rp2, col2, aggb, N_NODES);
    gemm_ln<<<391, 512, 0, stream>>>(aggb, xh, xh, Wcat + 196608,
                                     bias + 256, gamma + 256, beta + 256, h1);
    // layer 2
    gather_kernel<<<nb4, 256, 0, stream>>>(h1, rp1, col1, aggb, N_NODES);
    gemm_ln<<<391, 512, 0, stream>>>(aggb, h1, xh, Wcat,
                                     bias, gamma, beta, h2);
    // output: d_out = h2 @ Wout^T + bout (fp32)
    gemm_bt<<<dim3(391, 1), 256, 0, stream>>>(h2, 256, WoutH, 256,
                                              bias + 512, (float*)d_out, 128, 256, N_NODES);
}